// Round 1
// baseline (71919.745 us; speedup 1.0000x reference)
//
#include <hip/hip_runtime.h>
#include <math.h>

#define NN 4096
#define TT 64
#define HH 128
#define BQ 16
#define BK 32
#define SCALE 0.08838834764831845f  // 1/sqrt(128)

// ---------------------------------------------------------------------------
// Kernel A: per step, compute
//   h_in[n][j]   = relu(x[n,t]*W_in[0][j] + m[n,t]*W_in[1][j] + b_in[j])
//   h_proj[n][j] = sum_k h[n][k]*W_proj[k][j] + b_proj[j]
// grid: NN blocks of HH threads (one row per block).
// ---------------------------------------------------------------------------
__global__ __launch_bounds__(HH) void proj_kernel(
    const float* __restrict__ h,
    const float* __restrict__ x_seq, const float* __restrict__ m_seq,
    const float* __restrict__ W_in,  const float* __restrict__ b_in,
    const float* __restrict__ W_proj,const float* __restrict__ b_proj,
    float* __restrict__ h_proj, float* __restrict__ h_in, int t)
{
    __shared__ float sh[HH];
    const int n = blockIdx.x;
    const int j = threadIdx.x;
    sh[j] = h[n*HH + j];
    __syncthreads();
    float acc = b_proj[j];
    #pragma unroll 8
    for (int k = 0; k < HH; ++k)
        acc += sh[k] * W_proj[k*HH + j];   // coalesced over j; W_proj is L1/L2 resident
    h_proj[n*HH + j] = acc;

    const float xv = x_seq[n*TT + t];
    const float mv = m_seq[n*TT + t];
    float hi = xv * W_in[j] + mv * W_in[HH + j] + b_in[j];
    h_in[n*HH + j] = hi > 0.f ? hi : 0.f;
}

// ---------------------------------------------------------------------------
// Kernel B: flash-attention step + fused epilogue.
//   A = softmax(h_proj @ h_proj^T * scale); msg = A @ h_in
//   h_new = relu(msg @ W_gcn + b_gcn + h_in)  -> written back into h
//   pred  = h_new @ W_out + b_out             -> out[n*TT + t]
// grid: NN/BQ = 256 blocks of 256 threads. Online softmax over BK=32 key tiles.
// Thread map (score phase): tq=tid>>5 -> rows {2tq,2tq+1}; tk=tid&31 -> key tk.
// Thread map (PV phase):    same rows; d-slice d0=4*tk (float4 of msg).
// LDS: Qs 16x129 (pad: epilogue 4-row broadcast conflict-free), Ks 32x129
// (score reads (tk+d)%32 conflict-free), Vs 32x132 (float4 reads, 4-way=1.58x),
// Ps 16x33. Total ~44 KB.
// ---------------------------------------------------------------------------
__global__ __launch_bounds__(256) void attn_kernel(
    const float* __restrict__ h_proj, const float* __restrict__ h_in,
    const float* __restrict__ W_gcn,  const float* __restrict__ b_gcn,
    const float* __restrict__ W_out,  const float* __restrict__ b_out,
    float* __restrict__ h, float* __restrict__ out, int t)
{
    __shared__ float  Qs[BQ][HH+1];
    __shared__ float  Ks[BK][HH+1];
    __shared__ float4 Vs4[BK][33];      // row stride 132 floats
    __shared__ float  Ps[BQ][BK+1];
    float* Vs = (float*)Vs4;

    const int tid   = threadIdx.x;
    const int qbase = blockIdx.x * BQ;

    // stage Q block (16x128)
    for (int i = tid; i < BQ*HH; i += 256) {
        const int row = i >> 7, d = i & 127;
        Qs[row][d] = h_proj[(qbase + row)*HH + d];
    }

    const int tq = tid >> 5;        // 0..7
    const int tk = tid & 31;        // 0..31
    const int q0 = 2*tq;

    float m0 = -1e30f, m1 = -1e30f, l0 = 0.f, l1 = 0.f;
    float O0[4] = {0,0,0,0}, O1[4] = {0,0,0,0};

    for (int kb = 0; kb < NN/BK; ++kb) {
        __syncthreads();            // prev-iter PV reads done (also covers Q staging, iter 0)
        // stage K (scores) and V (h_in) tiles, coalesced
        for (int i = tid; i < BK*HH; i += 256) {
            const int row = i >> 7, d = i & 127;
            Ks[row][d]       = h_proj[(kb*BK + row)*HH + d];
            Vs[row*132 + d]  = h_in  [(kb*BK + row)*HH + d];
        }
        __syncthreads();

        // ---- scores: this thread computes s(q0,tk), s(q0+1,tk)
        float s0 = 0.f, s1 = 0.f;
        #pragma unroll 8
        for (int d = 0; d < HH; ++d) {
            const float kv = Ks[tk][d];
            s0 += Qs[q0][d]   * kv;   // broadcast reads across the 32-thread group
            s1 += Qs[q0+1][d] * kv;
        }
        s0 *= SCALE; s1 *= SCALE;

        // ---- online softmax: row max/sum across the 32 keys (half-wave shfl)
        float mx0 = s0, mx1 = s1;
        #pragma unroll
        for (int w = 1; w < 32; w <<= 1) {
            mx0 = fmaxf(mx0, __shfl_xor(mx0, w));
            mx1 = fmaxf(mx1, __shfl_xor(mx1, w));
        }
        const float mn0 = fmaxf(m0, mx0), mn1 = fmaxf(m1, mx1);
        const float a0  = __expf(m0 - mn0), a1 = __expf(m1 - mn1);
        const float p0  = __expf(s0 - mn0), p1 = __expf(s1 - mn1);
        float rs0 = p0, rs1 = p1;
        #pragma unroll
        for (int w = 1; w < 32; w <<= 1) {
            rs0 += __shfl_xor(rs0, w);
            rs1 += __shfl_xor(rs1, w);
        }
        l0 = l0*a0 + rs0; l1 = l1*a1 + rs1;
        m0 = mn0; m1 = mn1;
        Ps[q0][tk]   = p0;
        Ps[q0+1][tk] = p1;
        #pragma unroll
        for (int i = 0; i < 4; ++i) { O0[i] *= a0; O1[i] *= a1; }
        __syncthreads();

        // ---- PV: O[q][d0..d0+3] += sum_k P[q][k] * V[k][d0..d0+3]
        #pragma unroll 4
        for (int k = 0; k < BK; ++k) {
            const float pa = Ps[q0][k], pb = Ps[q0+1][k];
            const float4 v = Vs4[k][tk];
            O0[0] += pa*v.x; O0[1] += pa*v.y; O0[2] += pa*v.z; O0[3] += pa*v.w;
            O1[0] += pb*v.x; O1[1] += pb*v.y; O1[2] += pb*v.z; O1[3] += pb*v.w;
        }
    }
    __syncthreads();                 // last PV done before Qs reuse

    // msg = O/l  -> stash in Qs
    const int d0 = 4*tk;
    const float inv0 = 1.f/l0, inv1 = 1.f/l1;
    #pragma unroll
    for (int i = 0; i < 4; ++i) {
        Qs[q0][d0+i]   = O0[i]*inv0;
        Qs[q0+1][d0+i] = O1[i]*inv1;
    }
    __syncthreads();

    // ---- epilogue: h_new = relu(msg@W_gcn + b_gcn + h_in); pred = h_new@W_out + b_out
    const int r = tid >> 4, c = tid & 15, jj = c*8;
    float acc[8];
    #pragma unroll
    for (int i = 0; i < 8; ++i) acc[i] = b_gcn[jj+i];
    #pragma unroll 4
    for (int k = 0; k < HH; ++k) {
        const float mv = Qs[r][k];   // broadcast across 16 threads of the row
        const float4* wp = (const float4*)(W_gcn + k*HH + jj);
        const float4 w0 = wp[0], w1 = wp[1];
        acc[0] += mv*w0.x; acc[1] += mv*w0.y; acc[2] += mv*w0.z; acc[3] += mv*w0.w;
        acc[4] += mv*w1.x; acc[5] += mv*w1.y; acc[6] += mv*w1.z; acc[7] += mv*w1.w;
    }
    const float4* hi4 = (const float4*)(h_in + (qbase+r)*HH + jj);
    const float4 hi0 = hi4[0], hi1 = hi4[1];
    acc[0] += hi0.x; acc[1] += hi0.y; acc[2] += hi0.z; acc[3] += hi0.w;
    acc[4] += hi1.x; acc[5] += hi1.y; acc[6] += hi1.z; acc[7] += hi1.w;
    #pragma unroll
    for (int i = 0; i < 8; ++i) acc[i] = acc[i] > 0.f ? acc[i] : 0.f;

    float4* hp4 = (float4*)(h + (qbase+r)*HH + jj);
    hp4[0] = make_float4(acc[0],acc[1],acc[2],acc[3]);
    hp4[1] = make_float4(acc[4],acc[5],acc[6],acc[7]);

    float pp = 0.f;
    #pragma unroll
    for (int i = 0; i < 8; ++i) pp += acc[i]*W_out[jj+i];
    #pragma unroll
    for (int w = 1; w < 16; w <<= 1) pp += __shfl_xor(pp, w);
    if (c == 0) out[(qbase+r)*TT + t] = pp + b_out[0];
}

// ---------------------------------------------------------------------------
extern "C" void kernel_launch(void* const* d_in, const int* in_sizes, int n_in,
                              void* d_out, int out_size, void* d_ws, size_t ws_size,
                              hipStream_t stream) {
    const float* x_seq  = (const float*)d_in[0];
    const float* m_seq  = (const float*)d_in[1];
    const float* W_in   = (const float*)d_in[2];
    const float* b_in   = (const float*)d_in[3];
    const float* W_proj = (const float*)d_in[4];
    const float* b_proj = (const float*)d_in[5];
    const float* W_gcn  = (const float*)d_in[6];
    const float* b_gcn  = (const float*)d_in[7];
    const float* W_out  = (const float*)d_in[8];
    const float* b_out  = (const float*)d_in[9];
    float* out = (float*)d_out;

    // workspace: h | h_proj | h_in  (3 * N*H floats = 6 MB)
    float* h      = (float*)d_ws;
    float* h_proj = h + NN*HH;
    float* h_in   = h_proj + NN*HH;

    hipMemsetAsync(h, 0, NN*HH*sizeof(float), stream);  // h0 = 0 (ws is poisoned)

    for (int t = 0; t < TT; ++t) {
        proj_kernel<<<NN, HH, 0, stream>>>(h, x_seq, m_seq, W_in, b_in,
                                           W_proj, b_proj, h_proj, h_in, t);
        attn_kernel<<<NN/BQ, 256, 0, stream>>>(h_proj, h_in, W_gcn, b_gcn,
                                               W_out, b_out, h, out, t);
    }
}

// Round 3
// 3940.997 us; speedup vs baseline: 18.2491x; 18.2491x over previous
//
#include <hip/hip_runtime.h>
#include <math.h>

#define NN 4096
#define TT 64
#define HH 128
#define SPLITS 8
#define KEYS_PER_WAVE (NN / SPLITS)   // 512
#define SCALE 0.08838834764831845f    // 1/sqrt(128)
#define CSHIFT 16.0f

typedef __attribute__((ext_vector_type(8))) short short8;
typedef __attribute__((ext_vector_type(4))) float f32x4;
#define MFMA(a, b, c) __builtin_amdgcn_mfma_f32_16x16x32_bf16((a), (b), (c), 0, 0, 0)

// ---- bf16 helpers (RNE) ----
__device__ __forceinline__ short f2b(float f) {
    union { float f; unsigned u; } v; v.f = f;
    unsigned r = v.u + 0x7fffu + ((v.u >> 16) & 1u);
    return (short)(r >> 16);
}
__device__ __forceinline__ float b2f(short s) {
    union { unsigned u; float f; } v; v.u = ((unsigned)(unsigned short)s) << 16;
    return v.f;
}

// ===========================================================================
// prep: once per launch. Converts weights to bf16 transposed-for-B-frag
// layout, initializes hp = b_proj (h0 = 0), hin/hinT from x[:,0], m[:,0].
// ===========================================================================
__global__ __launch_bounds__(256) void prep_kernel(
    const float* __restrict__ x_seq, const float* __restrict__ m_seq,
    const float* __restrict__ W_in,  const float* __restrict__ b_in,
    const float* __restrict__ W_proj,const float* __restrict__ b_proj,
    const float* __restrict__ W_gcn,
    short* __restrict__ hp, short* __restrict__ hin, short* __restrict__ hinT,
    short* __restrict__ WgT, short* __restrict__ WpT)
{
    const int b = blockIdx.x, tid = threadIdx.x;
    if (b < 256) {
        const int n0 = b * 16;
        for (int i = tid; i < 16 * HH; i += 256) {
            const int q = i >> 7, j = i & 127, n = n0 + q;
            hp[n * HH + j] = f2b(b_proj[j]);
            float hi = x_seq[n * TT] * W_in[j] + m_seq[n * TT] * W_in[HH + j] + b_in[j];
            hi = hi > 0.f ? hi : 0.f;
            const short hb = f2b(hi);
            hin[n * HH + j] = hb;
            hinT[j * NN + n] = hb;
        }
    } else {
        const int wb = b - 256;                     // 0..15
        #pragma unroll
        for (int k = 0; k < 4; ++k) {
            const int idx = wb * 1024 + k * 256 + tid;   // = n*128 + kk
            const int n = idx >> 7, kk = idx & 127;
            WgT[idx] = f2b(W_gcn[kk * HH + n]);          // WgT[n][k] = W_gcn[k][n]
            WpT[idx] = f2b(W_proj[kk * HH + n]);
        }
    }
}

// ===========================================================================
// K2: attention partials. 1024 single-wave blocks (64 thr).
// Block = (qtile of 32 queries) x (key split of 512 keys).
// Fixed-shift softmax: p = exp(s*scale - C); partials are plain sums.
// Diagonal s_ii >= 0 guarantees the row denominator >= exp(-C) > 0.
// NOTE: the Pt D-layout->A-layout LDS round-trip REQUIRES __syncthreads()
// fences even single-wave: per-thread alias analysis would otherwise let the
// compiler hoist the ds_read above the cross-lane ds_write (round-2 NaN bug).
// ===========================================================================
__global__ __launch_bounds__(64) void attn_part_kernel(
    const short* __restrict__ hp, const short* __restrict__ hinT,
    float* __restrict__ Opart, float* __restrict__ lpart)
{
    __shared__ __align__(16) short Pt[32 * 40];   // stride 40 bf16 = 80B

    const int lane = threadIdx.x;
    const int ln = lane & 15, g = lane >> 4;
    const int qt = blockIdx.x >> 3, split = blockIdx.x & 7;
    const int q0 = qt * 32;

    // Q fragments: A-layout == 8 contiguous bf16 per lane, direct from global
    short8 qf[2][4];
    #pragma unroll
    for (int mt = 0; mt < 2; ++mt)
        #pragma unroll
        for (int kc = 0; kc < 4; ++kc)
            qf[mt][kc] = *(const short8*)&hp[(q0 + mt * 16 + ln) * HH + kc * 32 + g * 8];

    f32x4 oacc[2][8] = {};        // msg accumulators: 32q x 128d
    float lsum[2][4] = {};

    // K fragment double buffer (prefetch next tile)
    short8 kf[2][4], kf2[2][4];
    #pragma unroll
    for (int nt = 0; nt < 2; ++nt)
        #pragma unroll
        for (int kc = 0; kc < 4; ++kc)
            kf[nt][kc] = *(const short8*)&hp[(split * KEYS_PER_WAVE + nt * 16 + ln) * HH + kc * 32 + g * 8];

    for (int kt = 0; kt < KEYS_PER_WAVE / 32; ++kt) {
        const int kb = split * KEYS_PER_WAVE + kt * 32;

        // prefetch V fragments for this tile (B-layout: 8 contiguous keys from hinT row)
        short8 vf[8];
        #pragma unroll
        for (int dt = 0; dt < 8; ++dt)
            vf[dt] = *(const short8*)&hinT[(dt * 16 + ln) * NN + kb + g * 8];

        // prefetch next K tile
        const int kn = split * KEYS_PER_WAVE + (kt < KEYS_PER_WAVE / 32 - 1 ? (kt + 1) * 32 : kt * 32);
        #pragma unroll
        for (int nt = 0; nt < 2; ++nt)
            #pragma unroll
            for (int kc = 0; kc < 4; ++kc)
                kf2[nt][kc] = *(const short8*)&hp[(kn + nt * 16 + ln) * HH + kc * 32 + g * 8];

        // ---- scores: S[32x32] = Q(32x128) . K^T
        f32x4 sacc[2][2] = {};
        #pragma unroll
        for (int mt = 0; mt < 2; ++mt)
            #pragma unroll
            for (int nt = 0; nt < 2; ++nt)
                #pragma unroll
                for (int kc = 0; kc < 4; ++kc)
                    sacc[mt][nt] = MFMA(qf[mt][kc], kf[nt][kc], sacc[mt][nt]);

        __syncthreads();   // WAR guard: prev iteration's Pt reads complete before overwrite

        // ---- fixed-shift softmax numerators; P -> LDS (bf16), l accumulates rounded p
        #pragma unroll
        for (int mt = 0; mt < 2; ++mt)
            #pragma unroll
            for (int nt = 0; nt < 2; ++nt)
                #pragma unroll
                for (int r = 0; r < 4; ++r) {
                    const float p = __expf(sacc[mt][nt][r] * SCALE - CSHIFT);
                    const short pb = f2b(p);
                    lsum[mt][r] += b2f(pb);
                    Pt[(mt * 16 + g * 4 + r) * 40 + nt * 16 + ln] = pb;
                }

        __syncthreads();   // RAW guard: cross-lane Pt writes visible before A-frag reads

        // ---- P back as A-frags
        short8 pf0 = *(const short8*)&Pt[(ln) * 40 + g * 8];
        short8 pf1 = *(const short8*)&Pt[(16 + ln) * 40 + g * 8];

        // ---- PV: msg += P(32x32) . V(32x128)
        #pragma unroll
        for (int dt = 0; dt < 8; ++dt) {
            oacc[0][dt] = MFMA(pf0, vf[dt], oacc[0][dt]);
            oacc[1][dt] = MFMA(pf1, vf[dt], oacc[1][dt]);
        }

        #pragma unroll
        for (int nt = 0; nt < 2; ++nt)
            #pragma unroll
            for (int kc = 0; kc < 4; ++kc)
                kf[nt][kc] = kf2[nt][kc];
    }

    // ---- reduce l over the 16-lane key dim; write partials
    #pragma unroll
    for (int mt = 0; mt < 2; ++mt)
        #pragma unroll
        for (int r = 0; r < 4; ++r) {
            float l = lsum[mt][r];
            l += __shfl_xor(l, 1); l += __shfl_xor(l, 2);
            l += __shfl_xor(l, 4); l += __shfl_xor(l, 8);
            if (ln == 0) lpart[split * NN + q0 + mt * 16 + g * 4 + r] = l;
        }
    #pragma unroll
    for (int mt = 0; mt < 2; ++mt)
        #pragma unroll
        for (int dt = 0; dt < 8; ++dt)
            #pragma unroll
            for (int r = 0; r < 4; ++r)
                Opart[((size_t)split * NN + q0 + mt * 16 + g * 4 + r) * HH + dt * 16 + ln] = oacc[mt][dt][r];
}

// ===========================================================================
// K3: merge partials -> msg; h_new = relu(msg@Wg + b_gcn + h_in);
// pred -> out[:,t]; h_proj(t+1) = h_new@Wp + b_proj; h_in(t+1) from x,m.
// 256 single-wave blocks, 16 queries each. Each block touches only its own
// 16 rows of hp/hin/hinT -> no cross-block hazards.
// ===========================================================================
__global__ __launch_bounds__(64) void fuse_step_kernel(
    const float* __restrict__ Opart, const float* __restrict__ lpart,
    short* __restrict__ hp, short* __restrict__ hin, short* __restrict__ hinT,
    const short* __restrict__ WgT, const short* __restrict__ WpT,
    const float* __restrict__ b_gcn, const float* __restrict__ b_proj,
    const float* __restrict__ W_out, const float* __restrict__ b_out,
    const float* __restrict__ x_seq, const float* __restrict__ m_seq,
    const float* __restrict__ W_in,  const float* __restrict__ b_in,
    float* __restrict__ out, int t)
{
    __shared__ __align__(16) short msgb[16 * 136];   // stride 136 bf16 = 272B
    __shared__ __align__(16) short hnb[16 * 136];
    __shared__ float larr[16];

    const int lane = threadIdx.x, ln = lane & 15, g = lane >> 4;
    const int qb = blockIdx.x * 16;

    if (lane < 16) {
        float l = 0.f;
        #pragma unroll
        for (int sp = 0; sp < SPLITS; ++sp) l += lpart[sp * NN + qb + lane];
        larr[lane] = 1.0f / l;
    }
    __syncthreads();

    // merge 8 partials -> msg (bf16 into LDS, A-frag-readable row-major)
    for (int i = lane; i < 16 * HH; i += 64) {
        const int q = i >> 7, d = i & 127;
        float s = 0.f;
        #pragma unroll
        for (int sp = 0; sp < SPLITS; ++sp)
            s += Opart[((size_t)sp * NN + qb + q) * HH + d];
        msgb[q * 136 + d] = f2b(s * larr[q]);
    }
    __syncthreads();

    // ---- GEMM1: h_new = relu(msg @ W_gcn + b_gcn + h_in); pred partial
    short8 af[4];
    #pragma unroll
    for (int kc = 0; kc < 4; ++kc)
        af[kc] = *(const short8*)&msgb[ln * 136 + kc * 32 + g * 8];
    float pracc[4] = {0.f, 0.f, 0.f, 0.f};
    #pragma unroll
    for (int nt = 0; nt < 8; ++nt) {
        f32x4 c = {};
        #pragma unroll
        for (int kc = 0; kc < 4; ++kc)
            c = MFMA(af[kc], *(const short8*)&WgT[(nt * 16 + ln) * HH + kc * 32 + g * 8], c);
        const float bg = b_gcn[nt * 16 + ln];
        const float wo = W_out[nt * 16 + ln];
        #pragma unroll
        for (int r = 0; r < 4; ++r) {
            const int q = g * 4 + r;
            float v = c[r] + bg + b2f(hin[(qb + q) * HH + nt * 16 + ln]);
            v = v > 0.f ? v : 0.f;
            hnb[q * 136 + nt * 16 + ln] = f2b(v);
            pracc[r] += v * wo;
        }
    }
    #pragma unroll
    for (int r = 0; r < 4; ++r) {
        float p = pracc[r];
        p += __shfl_xor(p, 1); p += __shfl_xor(p, 2);
        p += __shfl_xor(p, 4); p += __shfl_xor(p, 8);
        if (ln == 0) out[(qb + g * 4 + r) * TT + t] = p + b_out[0];
    }
    __syncthreads();

    // ---- GEMM2: h_proj(t+1) = h_new @ W_proj + b_proj
    short8 hf[4];
    #pragma unroll
    for (int kc = 0; kc < 4; ++kc)
        hf[kc] = *(const short8*)&hnb[ln * 136 + kc * 32 + g * 8];
    #pragma unroll
    for (int nt = 0; nt < 8; ++nt) {
        f32x4 c = {};
        #pragma unroll
        for (int kc = 0; kc < 4; ++kc)
            c = MFMA(hf[kc], *(const short8*)&WpT[(nt * 16 + ln) * HH + kc * 32 + g * 8], c);
        const float bp = b_proj[nt * 16 + ln];
        #pragma unroll
        for (int r = 0; r < 4; ++r)
            hp[(qb + g * 4 + r) * HH + nt * 16 + ln] = f2b(c[r] + bp);
    }

    // ---- h_in(t+1)
    if (t < TT - 1) {
        for (int i = lane; i < 16 * HH; i += 64) {
            const int q = i >> 7, j = i & 127;
            float hi = x_seq[(qb + q) * TT + t + 1] * W_in[j]
                     + m_seq[(qb + q) * TT + t + 1] * W_in[HH + j] + b_in[j];
            hi = hi > 0.f ? hi : 0.f;
            const short hb = f2b(hi);
            hin[(qb + q) * HH + j] = hb;
            hinT[j * NN + qb + q] = hb;
        }
    }
}

// ===========================================================================
extern "C" void kernel_launch(void* const* d_in, const int* in_sizes, int n_in,
                              void* d_out, int out_size, void* d_ws, size_t ws_size,
                              hipStream_t stream) {
    const float* x_seq  = (const float*)d_in[0];
    const float* m_seq  = (const float*)d_in[1];
    const float* W_in   = (const float*)d_in[2];
    const float* b_in   = (const float*)d_in[3];
    const float* W_proj = (const float*)d_in[4];
    const float* b_proj = (const float*)d_in[5];
    const float* W_gcn  = (const float*)d_in[6];
    const float* b_gcn  = (const float*)d_in[7];
    const float* W_out  = (const float*)d_in[8];
    const float* b_out  = (const float*)d_in[9];
    float* out = (float*)d_out;

    // ws layout (~19.2 MB): hp | hin | hinT | WgT | WpT | lpart | Opart
    char* base = (char*)d_ws;
    short* hp    = (short*)(base);
    short* hin   = (short*)(base + (1 << 20));
    short* hinT  = (short*)(base + (2 << 20));
    short* WgT   = (short*)(base + (3 << 20));
    short* WpT   = (short*)(base + (3 << 20) + (32 << 10));
    float* lpart = (float*)(base + (3 << 20) + (64 << 10));
    float* Opart = (float*)(base + (3 << 20) + (192 << 10));

    prep_kernel<<<272, 256, 0, stream>>>(x_seq, m_seq, W_in, b_in, W_proj, b_proj,
                                         W_gcn, hp, hin, hinT, WgT, WpT);

    for (int t = 0; t < TT; ++t) {
        attn_part_kernel<<<(NN / 32) * SPLITS, 64, 0, stream>>>(hp, hinT, Opart, lpart);
        fuse_step_kernel<<<NN / 16, 64, 0, stream>>>(Opart, lpart, hp, hin, hinT,
                                                     WgT, WpT, b_gcn, b_proj, W_out, b_out,
                                                     x_seq, m_seq, W_in, b_in, out, t);
    }
}

// Round 4
// 3037.992 us; speedup vs baseline: 23.6735x; 1.2972x over previous
//
#include <hip/hip_runtime.h>
#include <math.h>

#define NN 4096
#define TT 64
#define HH 128
#define SPLITS 16
#define KPB (NN / SPLITS)    // 256 keys per block
#define KT 32                // key tile
#define NTILES (KPB / KT)    // 8
#define SCALE 0.08838834764831845f    // 1/sqrt(128)
#define CSHIFT 16.0f

typedef __attribute__((ext_vector_type(8))) short short8;
typedef __attribute__((ext_vector_type(4))) float f32x4;
#define MFMA(a, b, c) __builtin_amdgcn_mfma_f32_16x16x32_bf16((a), (b), (c), 0, 0, 0)

// ---- bf16 helpers (RNE) ----
__device__ __forceinline__ short f2b(float f) {
    union { float f; unsigned u; } v; v.f = f;
    unsigned r = v.u + 0x7fffu + ((v.u >> 16) & 1u);
    return (short)(r >> 16);
}
__device__ __forceinline__ float b2f(short s) {
    union { unsigned u; float f; } v; v.u = ((unsigned)(unsigned short)s) << 16;
    return v.f;
}

// ===========================================================================
// prep: once per launch. bf16 weight transposes; hp = b_proj (h0=0);
// hin/hinT from x[:,0], m[:,0].
// ===========================================================================
__global__ __launch_bounds__(256) void prep_kernel(
    const float* __restrict__ x_seq, const float* __restrict__ m_seq,
    const float* __restrict__ W_in,  const float* __restrict__ b_in,
    const float* __restrict__ W_proj,const float* __restrict__ b_proj,
    const float* __restrict__ W_gcn,
    short* __restrict__ hp, short* __restrict__ hin, short* __restrict__ hinT,
    short* __restrict__ WgT, short* __restrict__ WpT)
{
    const int b = blockIdx.x, tid = threadIdx.x;
    if (b < 256) {
        const int n0 = b * 16;
        for (int i = tid; i < 16 * HH; i += 256) {
            const int q = i >> 7, j = i & 127, n = n0 + q;
            hp[n * HH + j] = f2b(b_proj[j]);
            float hi = x_seq[n * TT] * W_in[j] + m_seq[n * TT] * W_in[HH + j] + b_in[j];
            hi = hi > 0.f ? hi : 0.f;
            const short hb = f2b(hi);
            hin[n * HH + j] = hb;
            hinT[j * NN + n] = hb;
        }
    } else {
        const int wb = b - 256;
        #pragma unroll
        for (int k = 0; k < 4; ++k) {
            const int idx = wb * 1024 + k * 256 + tid;   // = n*128 + kk
            const int n = idx >> 7, kk = idx & 127;
            WgT[idx] = f2b(W_gcn[kk * HH + n]);
            WpT[idx] = f2b(W_proj[kk * HH + n]);
        }
    }
}

// ===========================================================================
// K2: attention partials. 512 blocks x 256 thr (4 waves).
// Block = (128 q) x (256-key split); wave w owns q-subtile w*32..w*32+31.
// K/V tiles staged once per block in LDS (double-buffered), shared by waves.
// Fixed-shift softmax: p = exp(s*scale - C); diagonal s_ii>=0 => l >= e^-C.
// Pt LDS round-trip needs block fences (round-2 lesson: per-thread alias
// analysis will hoist the cross-lane ds_read otherwise).
// ===========================================================================
__global__ __launch_bounds__(256) void attn_part_kernel(
    const short* __restrict__ hp, const short* __restrict__ hinT,
    float* __restrict__ Opart, float* __restrict__ lpart)
{
    __shared__ __align__(16) short Kt[2][32 * 136];   // key rows x 128 d (pad->2-way banks)
    __shared__ __align__(16) short Vt[2][128 * 40];   // d rows x 32 keys (pad->2-way banks)
    __shared__ __align__(16) short Pt[4][32 * 40];    // per-wave P transpose buffer

    const int tid  = threadIdx.x;
    const int wave = tid >> 6, lane = tid & 63;
    const int ln = lane & 15, g = lane >> 4;
    const int qg = blockIdx.x >> 4, split = blockIdx.x & 15;
    const int q0 = qg * 128 + wave * 32;
    const int kbase = split * KPB;

    // Q fragments (A-layout = 8 contiguous bf16/lane), direct from global (L2-hot)
    short8 qf[2][4];
    #pragma unroll
    for (int mt = 0; mt < 2; ++mt)
        #pragma unroll
        for (int kc = 0; kc < 4; ++kc)
            qf[mt][kc] = *(const short8*)&hp[(q0 + mt * 16 + ln) * HH + kc * 32 + g * 8];

    f32x4 oacc[2][8] = {};
    float lsum[2][4] = {};

    // staging thread map (whole block cooperates)
    const int krow = tid >> 3, kcol = (tid & 7) * 16;   // 32 rows x 128 shorts
    const int vrow = tid >> 1, vcol = (tid & 1) * 16;   // 128 rows x 32 shorts
    short8 ksA, ksB, vsA, vsB;

    auto load_tile = [&](int kt_) {
        const int kb = kbase + kt_ * KT;
        ksA = *(const short8*)&hp  [(kb + krow) * HH + kcol];
        ksB = *(const short8*)&hp  [(kb + krow) * HH + kcol + 8];
        vsA = *(const short8*)&hinT[(size_t)vrow * NN + kb + vcol];
        vsB = *(const short8*)&hinT[(size_t)vrow * NN + kb + vcol + 8];
    };
    auto store_tile = [&](int b) {
        *(short8*)&Kt[b][krow * 136 + kcol]     = ksA;
        *(short8*)&Kt[b][krow * 136 + kcol + 8] = ksB;
        *(short8*)&Vt[b][vrow * 40 + vcol]      = vsA;
        *(short8*)&Vt[b][vrow * 40 + vcol + 8]  = vsB;
    };

    load_tile(0);
    store_tile(0);

    for (int kt = 0; kt < NTILES; ++kt) {
        const int b = kt & 1;
        __syncthreads();   // buf b fully staged; prev iter's Pt/frag reads done

        // K/V fragments from LDS (shared across the 4 waves)
        short8 kf[2][4], vf[8];
        #pragma unroll
        for (int nt = 0; nt < 2; ++nt)
            #pragma unroll
            for (int kc = 0; kc < 4; ++kc)
                kf[nt][kc] = *(const short8*)&Kt[b][(nt * 16 + ln) * 136 + kc * 32 + g * 8];
        #pragma unroll
        for (int dt = 0; dt < 8; ++dt)
            vf[dt] = *(const short8*)&Vt[b][(dt * 16 + ln) * 40 + g * 8];

        if (kt + 1 < NTILES) load_tile(kt + 1);   // issue early; stored after exp phase

        // ---- scores: S[32x32] = Q(32x128) . K^T
        f32x4 sacc[2][2] = {};
        #pragma unroll
        for (int mt = 0; mt < 2; ++mt)
            #pragma unroll
            for (int nt = 0; nt < 2; ++nt)
                #pragma unroll
                for (int kc = 0; kc < 4; ++kc)
                    sacc[mt][nt] = MFMA(qf[mt][kc], kf[nt][kc], sacc[mt][nt]);

        // ---- fixed-shift softmax numerators -> Pt (bf16); l sums rounded p
        #pragma unroll
        for (int mt = 0; mt < 2; ++mt)
            #pragma unroll
            for (int nt = 0; nt < 2; ++nt)
                #pragma unroll
                for (int r = 0; r < 4; ++r) {
                    const float p = __expf(sacc[mt][nt][r] * SCALE - CSHIFT);
                    const short pb = f2b(p);
                    lsum[mt][r] += b2f(pb);
                    Pt[wave][(mt * 16 + g * 4 + r) * 40 + nt * 16 + ln] = pb;
                }

        if (kt + 1 < NTILES) store_tile(b ^ 1);

        __syncthreads();   // Pt RAW fence (+ next-buf staging ordered before next top fence)

        short8 pf0 = *(const short8*)&Pt[wave][ln * 40 + g * 8];
        short8 pf1 = *(const short8*)&Pt[wave][(16 + ln) * 40 + g * 8];

        // ---- PV: msg += P(32x32) . V(32x128)
        #pragma unroll
        for (int dt = 0; dt < 8; ++dt) {
            oacc[0][dt] = MFMA(pf0, vf[dt], oacc[0][dt]);
            oacc[1][dt] = MFMA(pf1, vf[dt], oacc[1][dt]);
        }
    }

    // ---- l reduction over the 16-lane key dim; partial writes
    #pragma unroll
    for (int mt = 0; mt < 2; ++mt)
        #pragma unroll
        for (int r = 0; r < 4; ++r) {
            float l = lsum[mt][r];
            l += __shfl_xor(l, 1); l += __shfl_xor(l, 2);
            l += __shfl_xor(l, 4); l += __shfl_xor(l, 8);
            if (ln == 0) lpart[split * NN + q0 + mt * 16 + g * 4 + r] = l;
        }
    #pragma unroll
    for (int mt = 0; mt < 2; ++mt)
        #pragma unroll
        for (int dt = 0; dt < 8; ++dt)
            #pragma unroll
            for (int r = 0; r < 4; ++r)
                Opart[((size_t)split * NN + q0 + mt * 16 + g * 4 + r) * HH + dt * 16 + ln] = oacc[mt][dt][r];
}

// ===========================================================================
// K3: merge 16 partials -> msg; h_new = relu(msg@Wg + b_gcn + h_in);
// pred -> out[:,t]; h_proj(t+1) = h_new@Wp + b_proj; h_in(t+1).
// 256 blocks x 128 thr (2 waves; nt-dim split on the GEMMs).
// ===========================================================================
__global__ __launch_bounds__(128) void fuse_step_kernel(
    const float* __restrict__ Opart, const float* __restrict__ lpart,
    short* __restrict__ hp, short* __restrict__ hin, short* __restrict__ hinT,
    const short* __restrict__ WgT, const short* __restrict__ WpT,
    const float* __restrict__ b_gcn, const float* __restrict__ b_proj,
    const float* __restrict__ W_out, const float* __restrict__ b_out,
    const float* __restrict__ x_seq, const float* __restrict__ m_seq,
    const float* __restrict__ W_in,  const float* __restrict__ b_in,
    float* __restrict__ out, int t)
{
    __shared__ __align__(16) short msgb[16 * 136];
    __shared__ __align__(16) short hnb[16 * 136];
    __shared__ float larr[16];
    __shared__ float ppd[2][16];

    const int tid = threadIdx.x;
    const int wave = tid >> 6, lane = tid & 63;
    const int ln = lane & 15, g = lane >> 4;
    const int qb = blockIdx.x * 16;

    if (tid < 16) {
        float l = 0.f;
        #pragma unroll
        for (int sp = 0; sp < SPLITS; ++sp) l += lpart[sp * NN + qb + tid];
        larr[tid] = 1.0f / l;
    }
    __syncthreads();

    // merge 16 partial-sums -> msg (float4 reads; bf16 to LDS row-major)
    for (int i = tid; i < 16 * 32; i += 128) {
        const int q = i >> 5, d4 = (i & 31) * 4;
        f32x4 s = {};
        #pragma unroll
        for (int sp = 0; sp < SPLITS; ++sp)
            s += *(const f32x4*)&Opart[((size_t)sp * NN + qb + q) * HH + d4];
        const float inv = larr[q];
        short* mp = &msgb[q * 136 + d4];
        mp[0] = f2b(s[0] * inv); mp[1] = f2b(s[1] * inv);
        mp[2] = f2b(s[2] * inv); mp[3] = f2b(s[3] * inv);
    }
    __syncthreads();

    // ---- GEMM1: h_new = relu(msg @ W_gcn + b_gcn + h_in); pred partials
    short8 af[4];
    #pragma unroll
    for (int kc = 0; kc < 4; ++kc)
        af[kc] = *(const short8*)&msgb[ln * 136 + kc * 32 + g * 8];
    float pr[4] = {0.f, 0.f, 0.f, 0.f};
    #pragma unroll
    for (int ni = 0; ni < 4; ++ni) {
        const int nt = wave * 4 + ni;
        f32x4 c = {};
        #pragma unroll
        for (int kc = 0; kc < 4; ++kc)
            c = MFMA(af[kc], *(const short8*)&WgT[(nt * 16 + ln) * HH + kc * 32 + g * 8], c);
        const float bg = b_gcn[nt * 16 + ln];
        const float wo = W_out[nt * 16 + ln];
        #pragma unroll
        for (int r = 0; r < 4; ++r) {
            const int q = g * 4 + r;
            float v = c[r] + bg + b2f(hin[(qb + q) * HH + nt * 16 + ln]);
            v = v > 0.f ? v : 0.f;
            hnb[q * 136 + nt * 16 + ln] = f2b(v);
            pr[r] += v * wo;
        }
    }
    #pragma unroll
    for (int r = 0; r < 4; ++r) {
        float p = pr[r];
        p += __shfl_xor(p, 1); p += __shfl_xor(p, 2);
        p += __shfl_xor(p, 4); p += __shfl_xor(p, 8);
        if (ln == 0) ppd[wave][g * 4 + r] = p;
    }
    __syncthreads();   // hnb + ppd complete; hin reads done (update below is safe)

    if (tid < 16) out[(qb + tid) * TT + t] = ppd[0][tid] + ppd[1][tid] + b_out[0];

    // ---- GEMM2: h_proj(t+1) = h_new @ W_proj + b_proj
    short8 hf[4];
    #pragma unroll
    for (int kc = 0; kc < 4; ++kc)
        hf[kc] = *(const short8*)&hnb[ln * 136 + kc * 32 + g * 8];
    #pragma unroll
    for (int ni = 0; ni < 4; ++ni) {
        const int nt = wave * 4 + ni;
        f32x4 c = {};
        #pragma unroll
        for (int kc = 0; kc < 4; ++kc)
            c = MFMA(hf[kc], *(const short8*)&WpT[(nt * 16 + ln) * HH + kc * 32 + g * 8], c);
        const float bp = b_proj[nt * 16 + ln];
        #pragma unroll
        for (int r = 0; r < 4; ++r)
            hp[(qb + g * 4 + r) * HH + nt * 16 + ln] = f2b(c[r] + bp);
    }

    // ---- h_in(t+1)
    if (t < TT - 1) {
        for (int i = tid; i < 16 * HH; i += 128) {
            const int q = i >> 7, j = i & 127;
            float hi = x_seq[(qb + q) * TT + t + 1] * W_in[j]
                     + m_seq[(qb + q) * TT + t + 1] * W_in[HH + j] + b_in[j];
            hi = hi > 0.f ? hi : 0.f;
            const short hb = f2b(hi);
            hin[(qb + q) * HH + j] = hb;
            hinT[(size_t)j * NN + qb + q] = hb;
        }
    }
}

// ===========================================================================
extern "C" void kernel_launch(void* const* d_in, const int* in_sizes, int n_in,
                              void* d_out, int out_size, void* d_ws, size_t ws_size,
                              hipStream_t stream) {
    const float* x_seq  = (const float*)d_in[0];
    const float* m_seq  = (const float*)d_in[1];
    const float* W_in   = (const float*)d_in[2];
    const float* b_in   = (const float*)d_in[3];
    const float* W_proj = (const float*)d_in[4];
    const float* b_proj = (const float*)d_in[5];
    const float* W_gcn  = (const float*)d_in[6];
    const float* b_gcn  = (const float*)d_in[7];
    const float* W_out  = (const float*)d_in[8];
    const float* b_out  = (const float*)d_in[9];
    float* out = (float*)d_out;

    // ws layout (~36 MB): hp | hin | hinT | WgT | WpT | lpart | Opart
    char* base = (char*)d_ws;
    short* hp    = (short*)(base);
    short* hin   = (short*)(base + (1 << 20));
    short* hinT  = (short*)(base + (2 << 20));
    short* WgT   = (short*)(base + (3 << 20));
    short* WpT   = (short*)(base + (3 << 20) + (32 << 10));
    float* lpart = (float*)(base + (3 << 20) + (64 << 10));    // 256 KB
    float* Opart = (float*)(base + (4 << 20));                 // 32 MB

    prep_kernel<<<272, 256, 0, stream>>>(x_seq, m_seq, W_in, b_in, W_proj, b_proj,
                                         W_gcn, hp, hin, hinT, WgT, WpT);

    for (int t = 0; t < TT; ++t) {
        attn_part_kernel<<<(NN / 128) * SPLITS, 256, 0, stream>>>(hp, hinT, Opart, lpart);
        fuse_step_kernel<<<NN / 16, 128, 0, stream>>>(Opart, lpart, hp, hin, hinT,
                                                      WgT, WpT, b_gcn, b_proj, W_out, b_out,
                                                      x_seq, m_seq, W_in, b_in, out, t);
    }
}